// Round 4
// baseline (315.616 us; speedup 1.0000x reference)
//
#include <hip/hip_runtime.h>
#include <cstddef>

#define EPS 1e-5f

constexpr int NG  = 8192;   // genes
constexpr int HID = 32768;  // hidden (= NG*4)
constexpr int NTF = 1024;   // TFs
constexpr int B   = 256;    // batch

// INSTRUMENTATION BUILD: each kernel body repeats REP times (idempotent,
// barrier-protected) so both kernels exceed the 46us fill and surface in the
// rocprof top-5 with per-dispatch counters. Perf number this round is
// sacrificial; structure is identical to the R2 best (114.8 us).
#define REP 8

// round-to-nearest-even f32 -> bf16 bits (no NaN inputs in this problem)
static __device__ __forceinline__ unsigned short f2bf(float v) {
    union { float f; unsigned u; } a; a.f = v;
    unsigned r = a.u + 0x7fffu + ((a.u >> 16) & 1u);
    return (unsigned short)(r >> 16);
}

// ---------------------------------------------------------------------------
// Kernel 1: fused  sparse-L1 -> relu -> BN1 -> sparse-L2(4x4 blockdiag) -> relu
// (R2 version: single x pass, x in 32 VGPRs, 1024 blocks, 4/CU)
// ---------------------------------------------------------------------------
__global__ __launch_bounds__(256) void fused12(
    const float* __restrict__ x,       // [B][NG]
    const float* __restrict__ w1,      // [HID]
    const float* __restrict__ b1,      // [HID]
    const float* __restrict__ w2,      // [HID*4]
    const float* __restrict__ b2,      // [HID]
    unsigned short* __restrict__ h2b,  // [4][HID][64] bf16 bits
    float* __restrict__ m2g,           // [HID]
    float* __restrict__ inv2g)         // [HID]
{
    const int lane  = threadIdx.x & 31;   // column within 32-col tile
    const int slice = threadIdx.x >> 5;   // 8 slices x 32 rows
    const int c     = (blockIdx.x << 5) + lane;  // global hidden column
    const int g     = c >> 2;             // gene
    const int r0    = slice << 5;         // first batch row of my slice

    __shared__ float redA[8][32], redB[8][32];
    __shared__ float m1s[32], inv1s[32];

    const float w1c = w1[c], b1c = b1[c];
    const float* xp = x + (size_t)r0 * NG + g;

    for (int rep = 0; rep < REP; ++rep) {
        asm volatile("" ::: "memory");   // force real reloads each rep

        // ---- phase A: load x into registers; BN1 stats for column c ----
        float xv[32];
        float s = 0.f, s2 = 0.f;
        #pragma unroll
        for (int i = 0; i < 32; ++i) {
            float v = xp[(size_t)i * NG];
            xv[i] = v;
            float h = fmaxf(fmaf(w1c, v, b1c), 0.f);
            s += h;
            s2 = fmaf(h, h, s2);
        }
        redA[slice][lane] = s;
        redB[slice][lane] = s2;
        __syncthreads();
        if (threadIdx.x < 32) {
            float S = 0.f, S2 = 0.f;
            #pragma unroll
            for (int k = 0; k < 8; ++k) { S += redA[k][threadIdx.x]; S2 += redB[k][threadIdx.x]; }
            float m = S * (1.f / 256.f);
            float v = fmaf(-m, m, S2 * (1.f / 256.f));
            m1s[threadIdx.x]   = m;
            inv1s[threadIdx.x] = rsqrtf(v + EPS);
        }
        __syncthreads();

        // ---- fold BN1 into the 4x4 block weights ----
        const int lbase = lane & ~3;
        const int gbase = g << 2;
        float w1j[4], b1j[4], w2s[4];
        float bconst = b2[c];
        #pragma unroll
        for (int j = 0; j < 4; ++j) {
            w1j[j] = w1[gbase + j];
            b1j[j] = b1[gbase + j];
            float wv = w2[(c << 2) + j] * inv1s[lbase + j];
            w2s[j] = wv;
            bconst = fmaf(-wv, m1s[lbase + j], bconst);
        }

        // ---- phase B: recompute h1 from regs, folded L2, relu, BN2 stats ----
        float t2s = 0.f, t2s2 = 0.f;
        const int bt = slice >> 1;
        const int rr = (slice & 1) << 5;
        unsigned short* op = h2b + ((size_t)bt * HID + c) * 64 + rr;
        for (int i0 = 0; i0 < 32; i0 += 4) {
            ushort4 pk;
            unsigned short* pp = (unsigned short*)&pk;
            #pragma unroll
            for (int u = 0; u < 4; ++u) {
                float v = xv[i0 + u];
                float acc = bconst;
                #pragma unroll
                for (int j = 0; j < 4; ++j) {
                    float r = fmaxf(fmaf(w1j[j], v, b1j[j]), 0.f);
                    acc = fmaf(w2s[j], r, acc);
                }
                float r2 = fmaxf(acc, 0.f);
                t2s += r2;
                t2s2 = fmaf(r2, r2, t2s2);
                pp[u] = f2bf(r2);
            }
            *(ushort4*)(op + i0) = pk;
        }

        __syncthreads();
        redA[slice][lane] = t2s;
        redB[slice][lane] = t2s2;
        __syncthreads();
        if (threadIdx.x < 32) {
            float S = 0.f, S2 = 0.f;
            #pragma unroll
            for (int k = 0; k < 8; ++k) { S += redA[k][threadIdx.x]; S2 += redB[k][threadIdx.x]; }
            float m = S * (1.f / 256.f);
            float v = fmaf(-m, m, S2 * (1.f / 256.f));
            const int cw = (blockIdx.x << 5) + threadIdx.x;
            m2g[cw]   = m;
            inv2g[cw] = rsqrtf(v + EPS);
        }
        __syncthreads();   // protect redA/redB reuse across reps
    }
}

// ---------------------------------------------------------------------------
// Kernel 2: layer 3 gather-dot (BN2 folded into weights) + BN3 + output.
// (R2 version, batch-tile sweep + gene-contiguous uint4 loads)
// ---------------------------------------------------------------------------
__global__ __launch_bounds__(256) void fused3(
    const unsigned short* __restrict__ h2,  // [4][HID][64] bf16 bits
    const float* __restrict__ m2g,          // [HID]
    const float* __restrict__ inv2g,        // [HID]
    const float* __restrict__ w3,           // [NTF*256]
    const float* __restrict__ b3,           // [NTF]
    const int*   __restrict__ cols3,        // [NTF*256]
    float* __restrict__ out)                // [B][NTF]
{
    const int t   = blockIdx.x;
    const int tid = threadIdx.x;

    __shared__ float wls[256];
    __shared__ int   als[64];
    __shared__ float wred[4], rs[4], rs2[4];
    __shared__ float accq[32][64];
    __shared__ float red2[4][64];
    __shared__ float zs[256];

    for (int rep = 0; rep < REP; ++rep) {
        asm volatile("" ::: "memory");   // force real reloads each rep

        // fold BN2 into w3; accumulate bias correction (tid = edge index)
        int   col = cols3[(t << 8) + tid];
        float wv  = w3[(t << 8) + tid] * inv2g[col];
        wls[tid]  = wv;
        if (tid < 64) als[tid] = cols3[(t << 8) + (tid << 2)] << 7;
        float bp  = wv * m2g[col];
        #pragma unroll
        for (int o = 32; o > 0; o >>= 1) bp += __shfl_xor(bp, o);
        if ((tid & 63) == 0) wred[tid >> 6] = bp;
        __syncthreads();

        const char* h2c  = (const char*)h2;
        const int   lrow = (tid & 7) << 3;

        for (int bt = 0; bt < 4; ++bt) {
            float a0=0.f,a1=0.f,a2=0.f,a3=0.f,a4=0.f,a5=0.f,a6=0.f,a7=0.f;
            const char* bpt = h2c + (size_t)bt * ((size_t)HID * 128) + ((tid & 31) << 4);
            #pragma unroll
            for (int jb = 0; jb < 8; ++jb) {
                const int   j = (jb << 3) + (tid >> 5);
                const float w = wls[(jb << 5) + (tid >> 3)];
                const uint4 u = *(const uint4*)(bpt + als[j]);
                union { unsigned v; float f; } p0,p1,p2,p3,p4,p5,p6,p7;
                p0.v = u.x << 16; p1.v = u.x & 0xffff0000u;
                p2.v = u.y << 16; p3.v = u.y & 0xffff0000u;
                p4.v = u.z << 16; p5.v = u.z & 0xffff0000u;
                p6.v = u.w << 16; p7.v = u.w & 0xffff0000u;
                a0 = fmaf(w, p0.f, a0); a1 = fmaf(w, p1.f, a1);
                a2 = fmaf(w, p2.f, a2); a3 = fmaf(w, p3.f, a3);
                a4 = fmaf(w, p4.f, a4); a5 = fmaf(w, p5.f, a5);
                a6 = fmaf(w, p6.f, a6); a7 = fmaf(w, p7.f, a7);
            }
            __syncthreads();
            *(float4*)&accq[tid >> 3][lrow]     = make_float4(a0, a1, a2, a3);
            *(float4*)&accq[tid >> 3][lrow + 4] = make_float4(a4, a5, a6, a7);
            __syncthreads();
            {
                const int r = tid & 63, gq = tid >> 6;
                float p = 0.f;
                #pragma unroll
                for (int i = 0; i < 8; ++i) p += accq[(gq << 3) + i][r];
                red2[gq][r] = p;
            }
            __syncthreads();
            if (tid < 64)
                zs[(bt << 6) + tid] = red2[0][tid] + red2[1][tid]
                                    + red2[2][tid] + red2[3][tid];
        }
        __syncthreads();

        // BN3 over the 256 batch rows (tid = batch row now)
        const float zbias = b3[t] - (wred[0] + wred[1] + wred[2] + wred[3]);
        float z = zs[tid] + zbias;

        float s = z, s2 = z * z;
        #pragma unroll
        for (int o = 32; o > 0; o >>= 1) {
            s  += __shfl_xor(s, o);
            s2 += __shfl_xor(s2, o);
        }
        if ((tid & 63) == 0) { rs[tid >> 6] = s; rs2[tid >> 6] = s2; }
        __syncthreads();
        float S  = rs[0] + rs[1] + rs[2] + rs[3];
        float S2 = rs2[0] + rs2[1] + rs2[2] + rs2[3];
        float m  = S * (1.f / 256.f);
        float v  = fmaf(-m, m, S2 * (1.f / 256.f));
        float invs = rsqrtf(v + EPS);
        out[(size_t)tid * NTF + t] = (z - m) * invs;
        __syncthreads();   // protect wls/wred/zs reuse across reps
    }
}

// ---------------------------------------------------------------------------
extern "C" void kernel_launch(void* const* d_in, const int* in_sizes, int n_in,
                              void* d_out, int out_size, void* d_ws, size_t ws_size,
                              hipStream_t stream) {
    const float* x   = (const float*)d_in[0];
    const float* w1  = (const float*)d_in[1];
    const float* b1  = (const float*)d_in[2];
    const float* w2  = (const float*)d_in[3];
    const float* b2  = (const float*)d_in[4];
    const float* w3  = (const float*)d_in[5];
    const float* b3  = (const float*)d_in[6];
    const int* cols3 = (const int*)d_in[12];
    float* out = (float*)d_out;

    // workspace: h2b [4][HID][64] bf16 (16.8 MB) + m2 [HID] + inv2 [HID] f32
    unsigned short* h2b = (unsigned short*)d_ws;
    float* m2g   = (float*)(h2b + (size_t)HID * B);
    float* inv2g = m2g + HID;

    fused12<<<HID / 32, 256, 0, stream>>>(x, w1, b1, w2, b2, h2b, m2g, inv2g);
    fused3<<<NTF, 256, 0, stream>>>(h2b, m2g, inv2g, w3, b3, cols3, out);
}

// Round 5
// 117.563 us; speedup vs baseline: 2.6847x; 2.6847x over previous
//
#include <hip/hip_runtime.h>
#include <cstddef>

#define EPS 1e-5f

constexpr int NG  = 8192;   // genes
constexpr int HID = 32768;  // hidden (= NG*4)
constexpr int NTF = 1024;   // TFs
constexpr int B   = 256;    // batch

// round-to-nearest-even f32 -> bf16 bits (no NaN inputs in this problem)
static __device__ __forceinline__ unsigned short f2bf(float v) {
    union { float f; unsigned u; } a; a.f = v;
    unsigned r = a.u + 0x7fffu + ((a.u >> 16) & 1u);
    return (unsigned short)(r >> 16);
}

// ---------------------------------------------------------------------------
// Kernel 1: fused  sparse-L1 -> relu -> BN1 -> sparse-L2(4x4 blockdiag) -> relu
// R2 structure (single x pass, x in 32 VGPRs, 1024 blocks) + XCD swizzle:
// cb = ((bid&7)<<7)|(bid>>3) gives XCD x the contiguous column range
// [x*4096,(x+1)*4096) -> 4 KB/row of x per XCD -> full-cacheline L2 reuse
// (unswizzled, the 4 blocks sharing a 128 B x-line sit on 4 different XCDs).
// Writes relu(h2) batch-tile-major h2b[bt][c][64] bf16 + (mean2, invstd2).
// ---------------------------------------------------------------------------
__global__ __launch_bounds__(256) void fused12(
    const float* __restrict__ x,       // [B][NG]
    const float* __restrict__ w1,      // [HID]
    const float* __restrict__ b1,      // [HID]
    const float* __restrict__ w2,      // [HID*4]
    const float* __restrict__ b2,      // [HID]
    unsigned short* __restrict__ h2b,  // [4][HID][64] bf16 bits
    float* __restrict__ m2g,           // [HID]
    float* __restrict__ inv2g)         // [HID]
{
    const int lane  = threadIdx.x & 31;   // column within 32-col tile
    const int slice = threadIdx.x >> 5;   // 8 slices x 32 rows
    const int cb    = ((blockIdx.x & 7) << 7) | (blockIdx.x >> 3);  // XCD swizzle
    const int c     = (cb << 5) + lane;   // global hidden column
    const int g     = c >> 2;             // gene
    const int r0    = slice << 5;         // first batch row of my slice

    __shared__ float redA[8][32], redB[8][32];
    __shared__ float m1s[32], inv1s[32];

    const float w1c = w1[c], b1c = b1[c];
    const float* xp = x + (size_t)r0 * NG + g;

    // ---- phase A: load x once into registers; BN1 stats for column c ----
    float xv[32];
    float s = 0.f, s2 = 0.f;
    #pragma unroll
    for (int i = 0; i < 32; ++i) {
        float v = xp[(size_t)i * NG];
        xv[i] = v;
        float h = fmaxf(fmaf(w1c, v, b1c), 0.f);
        s += h;
        s2 = fmaf(h, h, s2);
    }
    redA[slice][lane] = s;
    redB[slice][lane] = s2;
    __syncthreads();
    if (threadIdx.x < 32) {
        float S = 0.f, S2 = 0.f;
        #pragma unroll
        for (int k = 0; k < 8; ++k) { S += redA[k][threadIdx.x]; S2 += redB[k][threadIdx.x]; }
        float m = S * (1.f / 256.f);
        float v = fmaf(-m, m, S2 * (1.f / 256.f));
        m1s[threadIdx.x]   = m;
        inv1s[threadIdx.x] = rsqrtf(v + EPS);
    }
    __syncthreads();

    // ---- fold BN1 into the 4x4 block weights ----
    const int lbase = lane & ~3;   // first column of my gene in LDS tile
    const int gbase = g << 2;      // first global column of my gene
    float w1j[4], b1j[4], w2s[4];
    float bconst = b2[c];
    #pragma unroll
    for (int j = 0; j < 4; ++j) {
        w1j[j] = w1[gbase + j];
        b1j[j] = b1[gbase + j];
        float wv = w2[(c << 2) + j] * inv1s[lbase + j];
        w2s[j] = wv;
        bconst = fmaf(-wv, m1s[lbase + j], bconst);
    }

    // ---- phase B: recompute h1 from registers, folded L2, relu, BN2 stats ----
    float t2s = 0.f, t2s2 = 0.f;
    const int bt = slice >> 1;            // 64-row batch tile
    const int rr = (slice & 1) << 5;      // row offset within tile (0 or 32)
    unsigned short* op = h2b + ((size_t)bt * HID + c) * 64 + rr;
    for (int i0 = 0; i0 < 32; i0 += 4) {
        ushort4 pk;
        unsigned short* pp = (unsigned short*)&pk;
        #pragma unroll
        for (int u = 0; u < 4; ++u) {
            float v = xv[i0 + u];
            float acc = bconst;
            #pragma unroll
            for (int j = 0; j < 4; ++j) {
                float r = fmaxf(fmaf(w1j[j], v, b1j[j]), 0.f);
                acc = fmaf(w2s[j], r, acc);
            }
            float r2 = fmaxf(acc, 0.f);
            t2s += r2;
            t2s2 = fmaf(r2, r2, t2s2);
            pp[u] = f2bf(r2);
        }
        *(ushort4*)(op + i0) = pk;   // 8 B store, aligned
    }

    __syncthreads();                 // phase-A reads of redA/redB done
    redA[slice][lane] = t2s;
    redB[slice][lane] = t2s2;
    __syncthreads();
    if (threadIdx.x < 32) {
        float S = 0.f, S2 = 0.f;
        #pragma unroll
        for (int k = 0; k < 8; ++k) { S += redA[k][threadIdx.x]; S2 += redB[k][threadIdx.x]; }
        float m = S * (1.f / 256.f);
        float v = fmaf(-m, m, S2 * (1.f / 256.f));
        const int cw = (cb << 5) + threadIdx.x;
        m2g[cw]   = m;
        inv2g[cw] = rsqrtf(v + EPS);
    }
}

// ---------------------------------------------------------------------------
// Kernel 2: layer-3 gather-dot, batch-half split for occupancy.
// Grid = NTF*2: t = bid>>1, half = bid&1 -> bt in {2*half, 2*half+1}.
// 2048 blocks -> 8 blocks/CU, 60 VGPR -> 8 waves/SIMD (was 4 blocks/CU, 50%).
// Same per-bt structure as R2 (gene-contiguous uint4 loads).  Each block
// computes the COMPLETE 256-edge dot for its 128 batch rows, adds the
// BN2-fold bias, writes zbuf[t][r].  bn3 does batch stats + output.
// ---------------------------------------------------------------------------
__global__ __launch_bounds__(256) void gather3(
    const unsigned short* __restrict__ h2,  // [4][HID][64] bf16 bits
    const float* __restrict__ m2g,          // [HID]
    const float* __restrict__ inv2g,        // [HID]
    const float* __restrict__ w3,           // [NTF*256]
    const float* __restrict__ b3,           // [NTF]
    const int*   __restrict__ cols3,        // [NTF*256]
    float* __restrict__ zbuf)               // [NTF][256] pre-BN z
{
    const int t    = blockIdx.x >> 1;
    const int half = blockIdx.x & 1;
    const int tid  = threadIdx.x;

    __shared__ float wls[256];
    __shared__ int   als[64];               // byte offset of gene base
    __shared__ float wred[4];
    __shared__ float accq[32][64];          // [edge-group][row-in-tile]
    __shared__ float red2[4][64];

    // fold BN2 into w3; accumulate bias correction (tid = edge index here)
    int   col = cols3[(t << 8) + tid];
    float wv  = w3[(t << 8) + tid] * inv2g[col];
    wls[tid]  = wv;
    if (tid < 64) als[tid] = cols3[(t << 8) + (tid << 2)] << 7;  // gene*4*128
    float bp  = wv * m2g[col];
    #pragma unroll
    for (int o = 32; o > 0; o >>= 1) bp += __shfl_xor(bp, o);
    if ((tid & 63) == 0) wred[tid >> 6] = bp;
    __syncthreads();

    const float zbias = b3[t] - (wred[0] + wred[1] + wred[2] + wred[3]);
    const char* h2c  = (const char*)h2;
    const int   lrow = (tid & 7) << 3;      // first of my 8 rows in the tile

    for (int bth = 0; bth < 2; ++bth) {
        const int bt = (half << 1) | bth;
        float a0=0.f,a1=0.f,a2=0.f,a3=0.f,a4=0.f,a5=0.f,a6=0.f,a7=0.f;
        const char* bpt = h2c + (size_t)bt * ((size_t)HID * 128) + ((tid & 31) << 4);
        #pragma unroll
        for (int jb = 0; jb < 8; ++jb) {
            const int   j = (jb << 3) + (tid >> 5);
            const float w = wls[(jb << 5) + (tid >> 3)];
            const uint4 u = *(const uint4*)(bpt + als[j]);   // 8 rows, 16 B
            union { unsigned v; float f; } p0,p1,p2,p3,p4,p5,p6,p7;
            p0.v = u.x << 16; p1.v = u.x & 0xffff0000u;
            p2.v = u.y << 16; p3.v = u.y & 0xffff0000u;
            p4.v = u.z << 16; p5.v = u.z & 0xffff0000u;
            p6.v = u.w << 16; p7.v = u.w & 0xffff0000u;
            a0 = fmaf(w, p0.f, a0); a1 = fmaf(w, p1.f, a1);
            a2 = fmaf(w, p2.f, a2); a3 = fmaf(w, p3.f, a3);
            a4 = fmaf(w, p4.f, a4); a5 = fmaf(w, p5.f, a5);
            a6 = fmaf(w, p6.f, a6); a7 = fmaf(w, p7.f, a7);
        }
        __syncthreads();   // prev phase's accq/red2 consumers done
        *(float4*)&accq[tid >> 3][lrow]     = make_float4(a0, a1, a2, a3);
        *(float4*)&accq[tid >> 3][lrow + 4] = make_float4(a4, a5, a6, a7);
        __syncthreads();
        {
            const int r = tid & 63, gq = tid >> 6;
            float p = 0.f;
            #pragma unroll
            for (int i = 0; i < 8; ++i) p += accq[(gq << 3) + i][r];
            red2[gq][r] = p;
        }
        __syncthreads();
        if (tid < 64)
            zbuf[(t << 8) + (bt << 6) + tid] =
                red2[0][tid] + red2[1][tid] + red2[2][tid] + red2[3][tid] + zbias;
    }
}

// ---------------------------------------------------------------------------
// Kernel 3: BN3 over the 256 batch rows + transposed output store.
// ---------------------------------------------------------------------------
__global__ __launch_bounds__(256) void bn3(
    const float* __restrict__ zbuf,   // [NTF][256]
    float* __restrict__ out)          // [B][NTF]
{
    const int t   = blockIdx.x;
    const int tid = threadIdx.x;
    __shared__ float rs[4], rs2[4];

    const float z = zbuf[(t << 8) + tid];

    float s = z, s2 = z * z;
    #pragma unroll
    for (int o = 32; o > 0; o >>= 1) {
        s  += __shfl_xor(s, o);
        s2 += __shfl_xor(s2, o);
    }
    if ((tid & 63) == 0) { rs[tid >> 6] = s; rs2[tid >> 6] = s2; }
    __syncthreads();
    float S  = rs[0] + rs[1] + rs[2] + rs[3];
    float S2 = rs2[0] + rs2[1] + rs2[2] + rs2[3];
    float m  = S * (1.f / 256.f);
    float v  = fmaf(-m, m, S2 * (1.f / 256.f));
    float invs = rsqrtf(v + EPS);
    out[(size_t)tid * NTF + t] = (z - m) * invs;
}

// ---------------------------------------------------------------------------
extern "C" void kernel_launch(void* const* d_in, const int* in_sizes, int n_in,
                              void* d_out, int out_size, void* d_ws, size_t ws_size,
                              hipStream_t stream) {
    const float* x   = (const float*)d_in[0];
    const float* w1  = (const float*)d_in[1];
    const float* b1  = (const float*)d_in[2];
    const float* w2  = (const float*)d_in[3];
    const float* b2  = (const float*)d_in[4];
    const float* w3  = (const float*)d_in[5];
    const float* b3  = (const float*)d_in[6];
    const int* cols3 = (const int*)d_in[12];
    float* out = (float*)d_out;

    // ws: h2b [4][HID][64] bf16 (16.8 MB) + m2/inv2 [HID] f32 + zbuf 1 MB
    unsigned short* h2b = (unsigned short*)d_ws;
    float* m2g   = (float*)(h2b + (size_t)HID * B);
    float* inv2g = m2g + HID;
    float* zbuf  = inv2g + HID;

    fused12<<<HID / 32, 256, 0, stream>>>(x, w1, b1, w2, b2, h2b, m2g, inv2g);
    gather3<<<NTF * 2, 256, 0, stream>>>(h2b, m2g, inv2g, w3, b3, cols3, zbuf);
    bn3<<<NTF, 256, 0, stream>>>(zbuf, out);
}

// Round 6
// 117.427 us; speedup vs baseline: 2.6878x; 1.0012x over previous
//
#include <hip/hip_runtime.h>
#include <cstddef>

#define EPS 1e-5f

constexpr int NG  = 8192;   // genes
constexpr int HID = 32768;  // hidden (= NG*4)
constexpr int NTF = 1024;   // TFs
constexpr int B   = 256;    // batch

// round-to-nearest-even f32 -> bf16 bits (no NaN inputs in this problem)
static __device__ __forceinline__ unsigned short f2bf(float v) {
    union { float f; unsigned u; } a; a.f = v;
    unsigned r = a.u + 0x7fffu + ((a.u >> 16) & 1u);
    return (unsigned short)(r >> 16);
}

// ---------------------------------------------------------------------------
// Kernel 1: fused  sparse-L1 -> relu -> BN1 -> sparse-L2(4x4 blockdiag) -> relu
// (R2 best version, unchanged: single x pass, x in 32 VGPRs, 1024 blocks,
// NO XCD swizzle — it was present in both regressing rounds R3/R5.)
// Writes relu(h2) batch-tile-major h2b[bt][c][64] bf16 + (mean2, invstd2).
// ---------------------------------------------------------------------------
__global__ __launch_bounds__(256) void fused12(
    const float* __restrict__ x,       // [B][NG]
    const float* __restrict__ w1,      // [HID]
    const float* __restrict__ b1,      // [HID]
    const float* __restrict__ w2,      // [HID*4]
    const float* __restrict__ b2,      // [HID]
    unsigned short* __restrict__ h2b,  // [4][HID][64] bf16 bits
    float* __restrict__ m2g,           // [HID]
    float* __restrict__ inv2g)         // [HID]
{
    const int lane  = threadIdx.x & 31;   // column within 32-col tile
    const int slice = threadIdx.x >> 5;   // 8 slices x 32 rows
    const int c     = (blockIdx.x << 5) + lane;  // global hidden column
    const int g     = c >> 2;             // gene
    const int r0    = slice << 5;         // first batch row of my slice

    __shared__ float redA[8][32], redB[8][32];
    __shared__ float m1s[32], inv1s[32];

    const float w1c = w1[c], b1c = b1[c];
    const float* xp = x + (size_t)r0 * NG + g;

    // ---- phase A: load x once into registers; BN1 stats for column c ----
    float xv[32];
    float s = 0.f, s2 = 0.f;
    #pragma unroll
    for (int i = 0; i < 32; ++i) {
        float v = xp[(size_t)i * NG];
        xv[i] = v;
        float h = fmaxf(fmaf(w1c, v, b1c), 0.f);
        s += h;
        s2 = fmaf(h, h, s2);
    }
    redA[slice][lane] = s;
    redB[slice][lane] = s2;
    __syncthreads();
    if (threadIdx.x < 32) {
        float S = 0.f, S2 = 0.f;
        #pragma unroll
        for (int k = 0; k < 8; ++k) { S += redA[k][threadIdx.x]; S2 += redB[k][threadIdx.x]; }
        float m = S * (1.f / 256.f);
        float v = fmaf(-m, m, S2 * (1.f / 256.f));
        m1s[threadIdx.x]   = m;
        inv1s[threadIdx.x] = rsqrtf(v + EPS);
    }
    __syncthreads();

    // ---- fold BN1 into the 4x4 block weights ----
    const int lbase = lane & ~3;   // first column of my gene in LDS tile
    const int gbase = g << 2;      // first global column of my gene
    float w1j[4], b1j[4], w2s[4];
    float bconst = b2[c];
    #pragma unroll
    for (int j = 0; j < 4; ++j) {
        w1j[j] = w1[gbase + j];
        b1j[j] = b1[gbase + j];
        float wv = w2[(c << 2) + j] * inv1s[lbase + j];
        w2s[j] = wv;
        bconst = fmaf(-wv, m1s[lbase + j], bconst);
    }

    // ---- phase B: recompute h1 from registers, folded L2, relu, BN2 stats ----
    float t2s = 0.f, t2s2 = 0.f;
    const int bt = slice >> 1;            // 64-row batch tile
    const int rr = (slice & 1) << 5;      // row offset within tile (0 or 32)
    unsigned short* op = h2b + ((size_t)bt * HID + c) * 64 + rr;
    for (int i0 = 0; i0 < 32; i0 += 4) {
        ushort4 pk;
        unsigned short* pp = (unsigned short*)&pk;
        #pragma unroll
        for (int u = 0; u < 4; ++u) {
            float v = xv[i0 + u];
            float acc = bconst;
            #pragma unroll
            for (int j = 0; j < 4; ++j) {
                float r = fmaxf(fmaf(w1j[j], v, b1j[j]), 0.f);
                acc = fmaf(w2s[j], r, acc);
            }
            float r2 = fmaxf(acc, 0.f);
            t2s += r2;
            t2s2 = fmaf(r2, r2, t2s2);
            pp[u] = f2bf(r2);
        }
        *(ushort4*)(op + i0) = pk;   // 8 B store, aligned
    }

    __syncthreads();                 // phase-A reads of redA/redB done
    redA[slice][lane] = t2s;
    redB[slice][lane] = t2s2;
    __syncthreads();
    if (threadIdx.x < 32) {
        float S = 0.f, S2 = 0.f;
        #pragma unroll
        for (int k = 0; k < 8; ++k) { S += redA[k][threadIdx.x]; S2 += redB[k][threadIdx.x]; }
        float m = S * (1.f / 256.f);
        float v = fmaf(-m, m, S2 * (1.f / 256.f));
        const int cw = (blockIdx.x << 5) + threadIdx.x;
        m2g[cw]   = m;
        inv2g[cw] = rsqrtf(v + EPS);
    }
}

// ---------------------------------------------------------------------------
// Kernel 2 (NEW): layer-3 gather-dot with a ZERO-SYNC main loop.
// Block = one TF.  Thread = (edge-octant q = tid>>5, row-slot r0 = tid&31):
// owns rows 8*r0..8*r0+7 (all in batch tile bt = r0>>3, row-offset (r0&7)*8)
// and edges q*32..q*32+31.  The 32 uint4 loads per thread are completely
// independent (address = LDS-cached cols3<<7 + fixed base) -> no
// __syncthreads from first to last load; unroll 8 keeps 8 loads in flight.
// Per wave-load, each 8-lane group covers one full 128 B line.
// Epilogue: accq[8][256] combine + BN3 (proven R2 reduce) + output.
// R2's version had 12 barrier drains here; that was the theory for its
// 18.4 us at 21% VALUBusy / low BW.
// ---------------------------------------------------------------------------
__global__ __launch_bounds__(256) void fused3(
    const unsigned short* __restrict__ h2,  // [4][HID][64] bf16 bits
    const float* __restrict__ m2g,          // [HID]
    const float* __restrict__ inv2g,        // [HID]
    const float* __restrict__ w3,           // [NTF*256]
    const float* __restrict__ b3,           // [NTF]
    const int*   __restrict__ cols3,        // [NTF*256]
    float* __restrict__ out)                // [B][NTF]
{
    const int t   = blockIdx.x;
    const int tid = threadIdx.x;

    __shared__ float wls[256];    // BN2-folded edge weights
    __shared__ int   eoff[256];   // byte offset of edge's column within a bt slab
    __shared__ float wred[4], rs[4], rs2[4];
    __shared__ float accq[8][256];

    // fold BN2 into w3; accumulate bias correction (tid = edge index here)
    const int   col = cols3[(t << 8) + tid];
    const float wv  = w3[(t << 8) + tid] * inv2g[col];
    wls[tid]  = wv;
    eoff[tid] = col << 7;                  // col * 64 rows * 2 B
    float bp  = wv * m2g[col];
    #pragma unroll
    for (int o = 32; o > 0; o >>= 1) bp += __shfl_xor(bp, o);
    if ((tid & 63) == 0) wred[tid >> 6] = bp;
    __syncthreads();

    // ---- zero-sync gather-dot ----
    const int q  = tid >> 5;               // edge octant
    const int r0 = tid & 31;               // row slot: rows 8r0..8r0+7
    const char* base = (const char*)h2
                     + (size_t)(r0 >> 3) * ((size_t)HID * 128)   // bt slab
                     + ((r0 & 7) << 4);                          // row byte off
    float a0=0.f,a1=0.f,a2=0.f,a3=0.f,a4=0.f,a5=0.f,a6=0.f,a7=0.f;
    #pragma unroll 8
    for (int k = 0; k < 32; ++k) {
        const int   e = (q << 5) + k;
        const float w = wls[e];
        const uint4 u = *(const uint4*)(base + eoff[e]);   // 8 rows, 16 B
        union { unsigned v; float f; } p0,p1,p2,p3,p4,p5,p6,p7;
        p0.v = u.x << 16; p1.v = u.x & 0xffff0000u;
        p2.v = u.y << 16; p3.v = u.y & 0xffff0000u;
        p4.v = u.z << 16; p5.v = u.z & 0xffff0000u;
        p6.v = u.w << 16; p7.v = u.w & 0xffff0000u;
        a0 = fmaf(w, p0.f, a0); a1 = fmaf(w, p1.f, a1);
        a2 = fmaf(w, p2.f, a2); a3 = fmaf(w, p3.f, a3);
        a4 = fmaf(w, p4.f, a4); a5 = fmaf(w, p5.f, a5);
        a6 = fmaf(w, p6.f, a6); a7 = fmaf(w, p7.f, a7);
    }
    *(float4*)&accq[q][(r0 << 3)]     = make_float4(a0, a1, a2, a3);
    *(float4*)&accq[q][(r0 << 3) + 4] = make_float4(a4, a5, a6, a7);
    __syncthreads();

    // ---- combine octants + BN3 over the 256 batch rows (tid = row now) ----
    const float zbias = b3[t] - (wred[0] + wred[1] + wred[2] + wred[3]);
    float z = zbias;
    #pragma unroll
    for (int qq = 0; qq < 8; ++qq) z += accq[qq][tid];

    float s = z, s2 = z * z;
    #pragma unroll
    for (int o = 32; o > 0; o >>= 1) {
        s  += __shfl_xor(s, o);
        s2 += __shfl_xor(s2, o);
    }
    if ((tid & 63) == 0) { rs[tid >> 6] = s; rs2[tid >> 6] = s2; }
    __syncthreads();
    float S  = rs[0] + rs[1] + rs[2] + rs[3];
    float S2 = rs2[0] + rs2[1] + rs2[2] + rs2[3];
    float m  = S * (1.f / 256.f);
    float v  = fmaf(-m, m, S2 * (1.f / 256.f));
    float invs = rsqrtf(v + EPS);
    out[(size_t)tid * NTF + t] = (z - m) * invs;
}

// ---------------------------------------------------------------------------
extern "C" void kernel_launch(void* const* d_in, const int* in_sizes, int n_in,
                              void* d_out, int out_size, void* d_ws, size_t ws_size,
                              hipStream_t stream) {
    const float* x   = (const float*)d_in[0];
    const float* w1  = (const float*)d_in[1];
    const float* b1  = (const float*)d_in[2];
    const float* w2  = (const float*)d_in[3];
    const float* b2  = (const float*)d_in[4];
    const float* w3  = (const float*)d_in[5];
    const float* b3  = (const float*)d_in[6];
    const int* cols3 = (const int*)d_in[12];
    float* out = (float*)d_out;

    // workspace: h2b [4][HID][64] bf16 (16.8 MB) + m2 [HID] + inv2 [HID] f32
    unsigned short* h2b = (unsigned short*)d_ws;
    float* m2g   = (float*)(h2b + (size_t)HID * B);
    float* inv2g = m2g + HID;

    fused12<<<HID / 32, 256, 0, stream>>>(x, w1, b1, w2, b2, h2b, m2g, inv2g);
    fused3<<<NTF, 256, 0, stream>>>(h2b, m2g, inv2g, w3, b3, cols3, out);
}

// Round 7
// 116.969 us; speedup vs baseline: 2.6983x; 1.0039x over previous
//
#include <hip/hip_runtime.h>
#include <cstddef>

#define EPS 1e-5f

constexpr int NG  = 8192;   // genes
constexpr int HID = 32768;  // hidden (= NG*4)
constexpr int NTF = 1024;   // TFs
constexpr int B   = 256;    // batch

// round-to-nearest-even f32 -> bf16 bits (no NaN inputs in this problem)
static __device__ __forceinline__ unsigned short f2bf(float v) {
    union { float f; unsigned u; } a; a.f = v;
    unsigned r = a.u + 0x7fffu + ((a.u >> 16) & 1u);
    return (unsigned short)(r >> 16);
}

// ---------------------------------------------------------------------------
// Kernel 1: fused  sparse-L1 -> relu -> BN1 -> sparse-L2(4x4 blockdiag) -> relu
// (R2 best version, unchanged.)
// Writes relu(h2) batch-tile-major h2b[bt][c][64] bf16 + (mean2, invstd2).
// ---------------------------------------------------------------------------
__global__ __launch_bounds__(256) void fused12(
    const float* __restrict__ x,       // [B][NG]
    const float* __restrict__ w1,      // [HID]
    const float* __restrict__ b1,      // [HID]
    const float* __restrict__ w2,      // [HID*4]
    const float* __restrict__ b2,      // [HID]
    unsigned short* __restrict__ h2b,  // [4][HID][64] bf16 bits
    float* __restrict__ m2g,           // [HID]
    float* __restrict__ inv2g)         // [HID]
{
    const int lane  = threadIdx.x & 31;   // column within 32-col tile
    const int slice = threadIdx.x >> 5;   // 8 slices x 32 rows
    const int c     = (blockIdx.x << 5) + lane;  // global hidden column
    const int g     = c >> 2;             // gene
    const int r0    = slice << 5;         // first batch row of my slice

    __shared__ float redA[8][32], redB[8][32];
    __shared__ float m1s[32], inv1s[32];

    const float w1c = w1[c], b1c = b1[c];
    const float* xp = x + (size_t)r0 * NG + g;

    // ---- phase A: load x once into registers; BN1 stats for column c ----
    float xv[32];
    float s = 0.f, s2 = 0.f;
    #pragma unroll
    for (int i = 0; i < 32; ++i) {
        float v = xp[(size_t)i * NG];
        xv[i] = v;
        float h = fmaxf(fmaf(w1c, v, b1c), 0.f);
        s += h;
        s2 = fmaf(h, h, s2);
    }
    redA[slice][lane] = s;
    redB[slice][lane] = s2;
    __syncthreads();
    if (threadIdx.x < 32) {
        float S = 0.f, S2 = 0.f;
        #pragma unroll
        for (int k = 0; k < 8; ++k) { S += redA[k][threadIdx.x]; S2 += redB[k][threadIdx.x]; }
        float m = S * (1.f / 256.f);
        float v = fmaf(-m, m, S2 * (1.f / 256.f));
        m1s[threadIdx.x]   = m;
        inv1s[threadIdx.x] = rsqrtf(v + EPS);
    }
    __syncthreads();

    // ---- fold BN1 into the 4x4 block weights ----
    const int lbase = lane & ~3;   // first column of my gene in LDS tile
    const int gbase = g << 2;      // first global column of my gene
    float w1j[4], b1j[4], w2s[4];
    float bconst = b2[c];
    #pragma unroll
    for (int j = 0; j < 4; ++j) {
        w1j[j] = w1[gbase + j];
        b1j[j] = b1[gbase + j];
        float wv = w2[(c << 2) + j] * inv1s[lbase + j];
        w2s[j] = wv;
        bconst = fmaf(-wv, m1s[lbase + j], bconst);
    }

    // ---- phase B: recompute h1 from registers, folded L2, relu, BN2 stats ----
    float t2s = 0.f, t2s2 = 0.f;
    const int bt = slice >> 1;            // 64-row batch tile
    const int rr = (slice & 1) << 5;      // row offset within tile (0 or 32)
    unsigned short* op = h2b + ((size_t)bt * HID + c) * 64 + rr;
    for (int i0 = 0; i0 < 32; i0 += 4) {
        ushort4 pk;
        unsigned short* pp = (unsigned short*)&pk;
        #pragma unroll
        for (int u = 0; u < 4; ++u) {
            float v = xv[i0 + u];
            float acc = bconst;
            #pragma unroll
            for (int j = 0; j < 4; ++j) {
                float r = fmaxf(fmaf(w1j[j], v, b1j[j]), 0.f);
                acc = fmaf(w2s[j], r, acc);
            }
            float r2 = fmaxf(acc, 0.f);
            t2s += r2;
            t2s2 = fmaf(r2, r2, t2s2);
            pp[u] = f2bf(r2);
        }
        *(ushort4*)(op + i0) = pk;   // 8 B store, aligned
    }

    __syncthreads();                 // phase-A reads of redA/redB done
    redA[slice][lane] = t2s;
    redB[slice][lane] = t2s2;
    __syncthreads();
    if (threadIdx.x < 32) {
        float S = 0.f, S2 = 0.f;
        #pragma unroll
        for (int k = 0; k < 8; ++k) { S += redA[k][threadIdx.x]; S2 += redB[k][threadIdx.x]; }
        float m = S * (1.f / 256.f);
        float v = fmaf(-m, m, S2 * (1.f / 256.f));
        const int cw = (blockIdx.x << 5) + threadIdx.x;
        m2g[cw]   = m;
        inv2g[cw] = rsqrtf(v + EPS);
    }
}

// ---------------------------------------------------------------------------
// Kernel 2: layer-3 gather-dot, zero-sync main loop (R6) + SORTED edge order.
// Prologue counting-sorts the 256 edges by column (bucket = col>>7, exact
// across buckets, arbitrary within — dot is permutation-invariant).  All
// 1024 blocks then sweep the column space in the same direction, so each
// XCD's resident blocks share ~8 aligned column windows (~2 MB) that fit
// its 4 MiB L2.  Theory: L2 hit rate 60% -> ~90% on the 134 MB gather.
// ---------------------------------------------------------------------------
__global__ __launch_bounds__(256) void fused3(
    const unsigned short* __restrict__ h2,  // [4][HID][64] bf16 bits
    const float* __restrict__ m2g,          // [HID]
    const float* __restrict__ inv2g,        // [HID]
    const float* __restrict__ w3,           // [NTF*256]
    const float* __restrict__ b3,           // [NTF]
    const int*   __restrict__ cols3,        // [NTF*256]
    float* __restrict__ out)                // [B][NTF]
{
    const int t   = blockIdx.x;
    const int tid = threadIdx.x;

    __shared__ float wls[256];    // BN2-folded edge weights, SORTED by col
    __shared__ int   eoff[256];   // byte offset of edge's column, SORTED
    __shared__ int   cnt[256];    // histogram / ticket counters
    __shared__ int   startb[256]; // exclusive bucket starts
    __shared__ int   wtot[4];
    __shared__ float wred[4], rs[4], rs2[4];
    __shared__ float accq[8][256];

    // ---- fold BN2 into w3; bias correction (order-independent) ----
    const int   col = cols3[(t << 8) + tid];
    const float wv  = w3[(t << 8) + tid] * inv2g[col];
    float bp  = wv * m2g[col];
    #pragma unroll
    for (int o = 32; o > 0; o >>= 1) bp += __shfl_xor(bp, o);
    if ((tid & 63) == 0) wred[tid >> 6] = bp;

    // ---- counting sort by bucket = col>>7 (256 buckets) ----
    const int bkt = col >> 7;
    cnt[tid] = 0;
    __syncthreads();
    atomicAdd(&cnt[bkt], 1);
    __syncthreads();
    // exclusive scan of cnt -> startb (wave shuffle scan + cross-wave combine)
    {
        const int c  = cnt[tid];
        int sc = c;
        #pragma unroll
        for (int d = 1; d < 64; d <<= 1) {
            int v = __shfl_up(sc, d);
            if ((tid & 63) >= d) sc += v;
        }
        if ((tid & 63) == 63) wtot[tid >> 6] = sc;
        __syncthreads();
        int wbase = 0;
        for (int w = 0; w < (tid >> 6); ++w) wbase += wtot[w];
        startb[tid] = wbase + sc - c;   // exclusive prefix
        cnt[tid] = 0;                   // reuse as ticket counter
    }
    __syncthreads();
    {
        const int pos = startb[bkt] + atomicAdd(&cnt[bkt], 1);
        wls[pos]  = wv;
        eoff[pos] = col << 7;           // col * 64 rows * 2 B
    }
    __syncthreads();

    // ---- zero-sync gather-dot over SORTED edges ----
    const int q  = tid >> 5;               // edge octant
    const int r0 = tid & 31;               // row slot: rows 8r0..8r0+7
    const char* base = (const char*)h2
                     + (size_t)(r0 >> 3) * ((size_t)HID * 128)   // bt slab
                     + ((r0 & 7) << 4);                          // row byte off
    float a0=0.f,a1=0.f,a2=0.f,a3=0.f,a4=0.f,a5=0.f,a6=0.f,a7=0.f;
    #pragma unroll 8
    for (int k = 0; k < 32; ++k) {
        const int   e = (q << 5) + k;
        const float w = wls[e];
        const uint4 u = *(const uint4*)(base + eoff[e]);   // 8 rows, 16 B
        union { unsigned v; float f; } p0,p1,p2,p3,p4,p5,p6,p7;
        p0.v = u.x << 16; p1.v = u.x & 0xffff0000u;
        p2.v = u.y << 16; p3.v = u.y & 0xffff0000u;
        p4.v = u.z << 16; p5.v = u.z & 0xffff0000u;
        p6.v = u.w << 16; p7.v = u.w & 0xffff0000u;
        a0 = fmaf(w, p0.f, a0); a1 = fmaf(w, p1.f, a1);
        a2 = fmaf(w, p2.f, a2); a3 = fmaf(w, p3.f, a3);
        a4 = fmaf(w, p4.f, a4); a5 = fmaf(w, p5.f, a5);
        a6 = fmaf(w, p6.f, a6); a7 = fmaf(w, p7.f, a7);
    }
    *(float4*)&accq[q][(r0 << 3)]     = make_float4(a0, a1, a2, a3);
    *(float4*)&accq[q][(r0 << 3) + 4] = make_float4(a4, a5, a6, a7);
    __syncthreads();

    // ---- combine octants + BN3 over the 256 batch rows (tid = row now) ----
    const float zbias = b3[t] - (wred[0] + wred[1] + wred[2] + wred[3]);
    float z = zbias;
    #pragma unroll
    for (int qq = 0; qq < 8; ++qq) z += accq[qq][tid];

    float s = z, s2 = z * z;
    #pragma unroll
    for (int o = 32; o > 0; o >>= 1) {
        s  += __shfl_xor(s, o);
        s2 += __shfl_xor(s2, o);
    }
    if ((tid & 63) == 0) { rs[tid >> 6] = s; rs2[tid >> 6] = s2; }
    __syncthreads();
    float S  = rs[0] + rs[1] + rs[2] + rs[3];
    float S2 = rs2[0] + rs2[1] + rs2[2] + rs2[3];
    float m  = S * (1.f / 256.f);
    float v  = fmaf(-m, m, S2 * (1.f / 256.f));
    float invs = rsqrtf(v + EPS);
    out[(size_t)tid * NTF + t] = (z - m) * invs;
}

// ---------------------------------------------------------------------------
extern "C" void kernel_launch(void* const* d_in, const int* in_sizes, int n_in,
                              void* d_out, int out_size, void* d_ws, size_t ws_size,
                              hipStream_t stream) {
    const float* x   = (const float*)d_in[0];
    const float* w1  = (const float*)d_in[1];
    const float* b1  = (const float*)d_in[2];
    const float* w2  = (const float*)d_in[3];
    const float* b2  = (const float*)d_in[4];
    const float* w3  = (const float*)d_in[5];
    const float* b3  = (const float*)d_in[6];
    const int* cols3 = (const int*)d_in[12];
    float* out = (float*)d_out;

    // workspace: h2b [4][HID][64] bf16 (16.8 MB) + m2 [HID] + inv2 [HID] f32
    unsigned short* h2b = (unsigned short*)d_ws;
    float* m2g   = (float*)(h2b + (size_t)HID * B);
    float* inv2g = m2g + HID;

    fused12<<<HID / 32, 256, 0, stream>>>(x, w1, b1, w2, b2, h2b, m2g, inv2g);
    fused3<<<NTF, 256, 0, stream>>>(h2b, m2g, inv2g, w3, b3, cols3, out);
}

// Round 8
// 114.716 us; speedup vs baseline: 2.7513x; 1.0196x over previous
//
#include <hip/hip_runtime.h>
#include <cstddef>

#define EPS 1e-5f

constexpr int NG  = 8192;   // genes
constexpr int HID = 32768;  // hidden (= NG*4)
constexpr int NTF = 1024;   // TFs
constexpr int B   = 256;    // batch

// round-to-nearest-even f32 -> bf16 bits (no NaN inputs in this problem)
static __device__ __forceinline__ unsigned short f2bf(float v) {
    union { float f; unsigned u; } a; a.f = v;
    unsigned r = a.u + 0x7fffu + ((a.u >> 16) & 1u);
    return (unsigned short)(r >> 16);
}

// ---------------------------------------------------------------------------
// FINAL (revert to R2 best, 114.8 us measured).
// Session evidence (R4 REP-instrumentation): fused12 ~10.3 us, fused3 ~18.4 us,
// harness-fixed ~86-88 us (268 MB poison-fill ~46 us at 73% HBM peak +
// restore/launch overhead).  Five structural fused3 variants (layout sweep,
// XCD partition, 2x occupancy, zero-sync loop, sorted gather) all measured
// flat within noise -> fused3 sits on the IC random-gather floor; kernel-side
// headroom is < 3% of total.  Keep the simplest best-measured form.
// ---------------------------------------------------------------------------

// ---------------------------------------------------------------------------
// Kernel 1: fused  sparse-L1 -> relu -> BN1 -> sparse-L2(4x4 blockdiag) -> relu
// Single x pass (x cached in 32 VGPRs), 1024 blocks (4/CU, 4 waves/SIMD).
// Block = 32 hidden columns x 8 batch-slices of 32 rows.
// Writes relu(h2) batch-tile-major h2b[bt][c][64] bf16 (bt=b>>6, r=b&63):
// 128 B per (bt,col); a gene's 4 cols are 512 B contiguous per batch tile.
// Emits per-column (mean2, invstd2) so BN2 folds into layer-3 weights.
// ---------------------------------------------------------------------------
__global__ __launch_bounds__(256) void fused12(
    const float* __restrict__ x,       // [B][NG]
    const float* __restrict__ w1,      // [HID]
    const float* __restrict__ b1,      // [HID]
    const float* __restrict__ w2,      // [HID*4]
    const float* __restrict__ b2,      // [HID]
    unsigned short* __restrict__ h2b,  // [4][HID][64] bf16 bits
    float* __restrict__ m2g,           // [HID]
    float* __restrict__ inv2g)         // [HID]
{
    const int lane  = threadIdx.x & 31;   // column within 32-col tile
    const int slice = threadIdx.x >> 5;   // 8 slices x 32 rows
    const int c     = (blockIdx.x << 5) + lane;  // global hidden column
    const int g     = c >> 2;             // gene
    const int r0    = slice << 5;         // first batch row of my slice

    __shared__ float redA[8][32], redB[8][32];
    __shared__ float m1s[32], inv1s[32];

    const float w1c = w1[c], b1c = b1[c];
    const float* xp = x + (size_t)r0 * NG + g;

    // ---- phase A: load x once into registers; BN1 stats for column c ----
    float xv[32];
    float s = 0.f, s2 = 0.f;
    #pragma unroll
    for (int i = 0; i < 32; ++i) {
        float v = xp[(size_t)i * NG];
        xv[i] = v;
        float h = fmaxf(fmaf(w1c, v, b1c), 0.f);
        s += h;
        s2 = fmaf(h, h, s2);
    }
    redA[slice][lane] = s;
    redB[slice][lane] = s2;
    __syncthreads();
    if (threadIdx.x < 32) {
        float S = 0.f, S2 = 0.f;
        #pragma unroll
        for (int k = 0; k < 8; ++k) { S += redA[k][threadIdx.x]; S2 += redB[k][threadIdx.x]; }
        float m = S * (1.f / 256.f);
        float v = fmaf(-m, m, S2 * (1.f / 256.f));
        m1s[threadIdx.x]   = m;
        inv1s[threadIdx.x] = rsqrtf(v + EPS);
    }
    __syncthreads();

    // ---- fold BN1 into the 4x4 block weights ----
    const int lbase = lane & ~3;   // first column of my gene in LDS tile
    const int gbase = g << 2;      // first global column of my gene
    float w1j[4], b1j[4], w2s[4];
    float bconst = b2[c];
    #pragma unroll
    for (int j = 0; j < 4; ++j) {
        w1j[j] = w1[gbase + j];
        b1j[j] = b1[gbase + j];
        float wv = w2[(c << 2) + j] * inv1s[lbase + j];
        w2s[j] = wv;
        bconst = fmaf(-wv, m1s[lbase + j], bconst);
    }

    // ---- phase B: recompute h1 from registers, folded L2, relu, BN2 stats ----
    float t2s = 0.f, t2s2 = 0.f;
    const int bt = slice >> 1;            // 64-row batch tile
    const int rr = (slice & 1) << 5;      // row offset within tile (0 or 32)
    unsigned short* op = h2b + ((size_t)bt * HID + c) * 64 + rr;
    for (int i0 = 0; i0 < 32; i0 += 4) {
        ushort4 pk;
        unsigned short* pp = (unsigned short*)&pk;
        #pragma unroll
        for (int u = 0; u < 4; ++u) {
            float v = xv[i0 + u];
            float acc = bconst;
            #pragma unroll
            for (int j = 0; j < 4; ++j) {
                float r = fmaxf(fmaf(w1j[j], v, b1j[j]), 0.f);
                acc = fmaf(w2s[j], r, acc);
            }
            float r2 = fmaxf(acc, 0.f);
            t2s += r2;
            t2s2 = fmaf(r2, r2, t2s2);
            pp[u] = f2bf(r2);
        }
        *(ushort4*)(op + i0) = pk;   // 8 B store, aligned
    }

    __syncthreads();                 // phase-A reads of redA/redB done
    redA[slice][lane] = t2s;
    redB[slice][lane] = t2s2;
    __syncthreads();
    if (threadIdx.x < 32) {
        float S = 0.f, S2 = 0.f;
        #pragma unroll
        for (int k = 0; k < 8; ++k) { S += redA[k][threadIdx.x]; S2 += redB[k][threadIdx.x]; }
        float m = S * (1.f / 256.f);
        float v = fmaf(-m, m, S2 * (1.f / 256.f));
        const int cw = (blockIdx.x << 5) + threadIdx.x;
        m2g[cw]   = m;
        inv2g[cw] = rsqrtf(v + EPS);
    }
}

// ---------------------------------------------------------------------------
// Kernel 2: layer 3 gather-dot (BN2 folded into weights) + BN3 + output.
// Block = one TF.  Batch-tile sweep bt=0..3; gene-contiguous uint4 loads
// (each wave covers 1 KB fully sequential; 32 x 16 B loads/thread).
// ---------------------------------------------------------------------------
__global__ __launch_bounds__(256) void fused3(
    const unsigned short* __restrict__ h2,  // [4][HID][64] bf16 bits
    const float* __restrict__ m2g,          // [HID]
    const float* __restrict__ inv2g,        // [HID]
    const float* __restrict__ w3,           // [NTF*256]
    const float* __restrict__ b3,           // [NTF]
    const int*   __restrict__ cols3,        // [NTF*256]
    float* __restrict__ out)                // [B][NTF]
{
    const int t   = blockIdx.x;
    const int tid = threadIdx.x;

    __shared__ float wls[256];
    __shared__ int   als[64];               // byte offset of gene base (gene*512)
    __shared__ float wred[4], rs[4], rs2[4];
    __shared__ float accq[32][64];          // [edge-group][row-in-tile]
    __shared__ float red2[4][64];
    __shared__ float zs[256];               // pre-bias dot per batch row

    // fold BN2 into w3; accumulate bias correction (tid = edge index here)
    int   col = cols3[(t << 8) + tid];
    float wv  = w3[(t << 8) + tid] * inv2g[col];
    wls[tid]  = wv;
    if (tid < 64) als[tid] = cols3[(t << 8) + (tid << 2)] << 7;  // gene*4*128
    float bp  = wv * m2g[col];
    #pragma unroll
    for (int o = 32; o > 0; o >>= 1) bp += __shfl_xor(bp, o);
    if ((tid & 63) == 0) wred[tid >> 6] = bp;
    __syncthreads();

    const char* h2c  = (const char*)h2;
    const int   lrow = (tid & 7) << 3;      // first of my 8 rows in the tile

    for (int bt = 0; bt < 4; ++bt) {
        float a0=0.f,a1=0.f,a2=0.f,a3=0.f,a4=0.f,a5=0.f,a6=0.f,a7=0.f;
        const char* bpt = h2c + (size_t)bt * ((size_t)HID * 128) + ((tid & 31) << 4);
        #pragma unroll
        for (int jb = 0; jb < 8; ++jb) {
            const int   j = (jb << 3) + (tid >> 5);
            const float w = wls[(jb << 5) + (tid >> 3)];
            const uint4 u = *(const uint4*)(bpt + als[j]);   // 8 rows, 16 B
            union { unsigned v; float f; } p0,p1,p2,p3,p4,p5,p6,p7;
            p0.v = u.x << 16; p1.v = u.x & 0xffff0000u;
            p2.v = u.y << 16; p3.v = u.y & 0xffff0000u;
            p4.v = u.z << 16; p5.v = u.z & 0xffff0000u;
            p6.v = u.w << 16; p7.v = u.w & 0xffff0000u;
            a0 = fmaf(w, p0.f, a0); a1 = fmaf(w, p1.f, a1);
            a2 = fmaf(w, p2.f, a2); a3 = fmaf(w, p3.f, a3);
            a4 = fmaf(w, p4.f, a4); a5 = fmaf(w, p5.f, a5);
            a6 = fmaf(w, p6.f, a6); a7 = fmaf(w, p7.f, a7);
        }
        __syncthreads();   // prev tile's accq/red2 consumers done
        *(float4*)&accq[tid >> 3][lrow]     = make_float4(a0, a1, a2, a3);
        *(float4*)&accq[tid >> 3][lrow + 4] = make_float4(a4, a5, a6, a7);
        __syncthreads();
        {
            const int r = tid & 63, gq = tid >> 6;
            float p = 0.f;
            #pragma unroll
            for (int i = 0; i < 8; ++i) p += accq[(gq << 3) + i][r];
            red2[gq][r] = p;
        }
        __syncthreads();
        if (tid < 64)
            zs[(bt << 6) + tid] = red2[0][tid] + red2[1][tid]
                                + red2[2][tid] + red2[3][tid];
    }
    __syncthreads();

    // BN3 over the 256 batch rows (tid = batch row now)
    const float zbias = b3[t] - (wred[0] + wred[1] + wred[2] + wred[3]);
    float z = zs[tid] + zbias;

    float s = z, s2 = z * z;
    #pragma unroll
    for (int o = 32; o > 0; o >>= 1) {
        s  += __shfl_xor(s, o);
        s2 += __shfl_xor(s2, o);
    }
    if ((tid & 63) == 0) { rs[tid >> 6] = s; rs2[tid >> 6] = s2; }
    __syncthreads();
    float S  = rs[0] + rs[1] + rs[2] + rs[3];
    float S2 = rs2[0] + rs2[1] + rs2[2] + rs2[3];
    float m  = S * (1.f / 256.f);
    float v  = fmaf(-m, m, S2 * (1.f / 256.f));
    float invs = rsqrtf(v + EPS);
    out[(size_t)tid * NTF + t] = (z - m) * invs;
}

// ---------------------------------------------------------------------------
extern "C" void kernel_launch(void* const* d_in, const int* in_sizes, int n_in,
                              void* d_out, int out_size, void* d_ws, size_t ws_size,
                              hipStream_t stream) {
    const float* x   = (const float*)d_in[0];
    const float* w1  = (const float*)d_in[1];
    const float* b1  = (const float*)d_in[2];
    const float* w2  = (const float*)d_in[3];
    const float* b2  = (const float*)d_in[4];
    const float* w3  = (const float*)d_in[5];
    const float* b3  = (const float*)d_in[6];
    const int* cols3 = (const int*)d_in[12];
    float* out = (float*)d_out;

    // workspace: h2b [4][HID][64] bf16 (16.8 MB) + m2 [HID] + inv2 [HID] f32
    unsigned short* h2b = (unsigned short*)d_ws;
    float* m2g   = (float*)(h2b + (size_t)HID * B);
    float* inv2g = m2g + HID;

    fused12<<<HID / 32, 256, 0, stream>>>(x, w1, b1, w2, b2, h2b, m2g, inv2g);
    fused3<<<NTF, 256, 0, stream>>>(h2b, m2g, inv2g, w3, b3, cols3, out);
}